// Round 2
// baseline (1464.700 us; speedup 1.0000x reference)
//
#include <hip/hip_runtime.h>

typedef unsigned short u16;
typedef float f32x4 __attribute__((ext_vector_type(4)));
typedef short s16x8 __attribute__((ext_vector_type(8)));
typedef u16   u16x4 __attribute__((ext_vector_type(4)));

#define DEV static __device__ __forceinline__

DEV u16 f2b(float f){
  unsigned u = __builtin_bit_cast(unsigned, f);
  u += 0x7fffu + ((u >> 16) & 1u);
  return (u16)(u >> 16);
}
DEV float b2f(u16 h){ unsigned u = ((unsigned)h) << 16; return __builtin_bit_cast(float, u); }

constexpr int TT = 1024, DM = 1024, NE = 8, FFD = 4096;
constexpr int NTOK = 4096;
constexpr float L2E = 1.4426950408889634f;

// ---------------- transpose fp32 [R][C] -> bf16 hi/lo [C][R] ----------------
struct Ptr8 { const float* p[8]; };

__global__ __launch_bounds__(256) void trans8_k(Ptr8 srcs, u16* __restrict__ dh, u16* __restrict__ dl){
  __shared__ float tl[64][65];
  const float* src = srcs.p[blockIdx.z];
  u16* dsth = dh + (size_t)blockIdx.z * 1024 * 1024;
  u16* dstl = dl + (size_t)blockIdx.z * 1024 * 1024;
  const int tid = threadIdx.x;
  const int r0 = blockIdx.y * 64, c0 = blockIdx.x * 64;
  const int ty = tid >> 4, tx = tid & 15;
#pragma unroll
  for (int i = 0; i < 4; i++){
    int row = ty + i * 16;
    f32x4 v = *(const f32x4*)&src[(size_t)(r0 + row) * 1024 + c0 + tx * 4];
#pragma unroll
    for (int j = 0; j < 4; j++) tl[row][tx * 4 + j] = v[j];
  }
  __syncthreads();
#pragma unroll
  for (int i = 0; i < 4; i++){
    int drow = ty + i * 16;
    u16x4 oh, ol;
#pragma unroll
    for (int j = 0; j < 4; j++){
      float v = tl[tx * 4 + j][drow];
      u16 hh = f2b(v);
      oh[j] = hh; ol[j] = f2b(v - b2f(hh));
    }
    *(u16x4*)&dsth[(size_t)(c0 + drow) * 1024 + r0 + tx * 4] = oh;
    *(u16x4*)&dstl[(size_t)(c0 + drow) * 1024 + r0 + tx * 4] = ol;
  }
}

// single-bf16 transpose for MoE weights
__global__ __launch_bounds__(256) void transb_k(const float* __restrict__ src0, u16* __restrict__ dst0, int R, int C){
  __shared__ float tl[64][65];
  const float* src = src0 + (size_t)blockIdx.z * R * C;
  u16* dst = dst0 + (size_t)blockIdx.z * R * C;
  const int tid = threadIdx.x;
  const int r0 = blockIdx.y * 64, c0 = blockIdx.x * 64;
  const int ty = tid >> 4, tx = tid & 15;
#pragma unroll
  for (int i = 0; i < 4; i++){
    int row = ty + i * 16;
    f32x4 v = *(const f32x4*)&src[(size_t)(r0 + row) * C + c0 + tx * 4];
#pragma unroll
    for (int j = 0; j < 4; j++) tl[row][tx * 4 + j] = v[j];
  }
  __syncthreads();
#pragma unroll
  for (int i = 0; i < 4; i++){
    int drow = ty + i * 16;
    u16x4 o;
#pragma unroll
    for (int j = 0; j < 4; j++) o[j] = f2b(tl[tx * 4 + j][drow]);
    *(u16x4*)&dst[(size_t)(c0 + drow) * R + r0 + tx * 4] = o;
  }
}

// ---------------- layernorm (fp32 in, fp32 and/or bf16 out) ----------------
__global__ __launch_bounds__(256) void ln_k(const float* __restrict__ x, const float* __restrict__ g,
                                            const float* __restrict__ b,
                                            float* __restrict__ outF, u16* __restrict__ outB){
  __shared__ float red[8];
  const int row = blockIdx.x, tid = threadIdx.x, l = tid & 63, wave = tid >> 6;
  f32x4 v = *(const f32x4*)&x[(size_t)row * DM + tid * 4];
  float s = v[0] + v[1] + v[2] + v[3];
  float sq = v[0]*v[0] + v[1]*v[1] + v[2]*v[2] + v[3]*v[3];
#pragma unroll
  for (int m = 1; m < 64; m <<= 1){ s += __shfl_xor(s, m); sq += __shfl_xor(sq, m); }
  if (l == 0){ red[wave] = s; red[4 + wave] = sq; }
  __syncthreads();
  float tot = red[0] + red[1] + red[2] + red[3];
  float totq = red[4] + red[5] + red[6] + red[7];
  float mean = tot * (1.0f / DM);
  float var = totq * (1.0f / DM) - mean * mean;
  float rstd = rsqrtf(var + 1e-5f);
  f32x4 gg = *(const f32x4*)&g[tid * 4];
  f32x4 bb = *(const f32x4*)&b[tid * 4];
  f32x4 of; u16x4 ob;
#pragma unroll
  for (int j = 0; j < 4; j++){
    float y = (v[j] - mean) * rstd * gg[j] + bb[j];
    of[j] = y; ob[j] = f2b(y);
  }
  if (outF) *(f32x4*)&outF[(size_t)row * DM + tid * 4] = of;
  if (outB) *(u16x4*)&outB[(size_t)row * DM + tid * 4] = ob;
}

// ---------------- split-precision GEMM: C = A(f32)[M][K] * B^T(hi/lo)[N][K] ----------------
// 3-term MFMA: Ah*Bh + Ah*Bl + Al*Bh. VTR=1: write bf16 hi/lo to V^T global layout.
template<int VTR>
__global__ __launch_bounds__(256) void gemm_sp_k(
    const float* __restrict__ A, const u16* __restrict__ Bth, const u16* __restrict__ Btl,
    const float* __restrict__ bias, const float* __restrict__ res,
    float* __restrict__ Cf, u16* __restrict__ Ch, u16* __restrict__ Cl,
    int M, int N, int K)
{
  __shared__ alignas(16) u16 Ah[128 * 32], Al[128 * 32];
  __shared__ alignas(16) u16 Bh[128 * 32], Bl[128 * 32];
  const int tid = threadIdx.x, l = tid & 63, wave = tid >> 6;
  const int m0 = blockIdx.y * 128, n0 = blockIdx.x * 128;
  const int r0 = tid >> 2, seg = (tid & 3) * 8;
  const float* Ag0 = A + (size_t)(m0 + r0) * K + seg;
  const float* Ag1 = Ag0 + (size_t)64 * K;
  const u16* Bh0 = Bth + (size_t)(n0 + r0) * K + seg;
  const u16* Bh1 = Bh0 + (size_t)64 * K;
  const u16* Bl0 = Btl + (size_t)(n0 + r0) * K + seg;
  const u16* Bl1 = Bl0 + (size_t)64 * K;
  f32x4 acc[4][4];
#pragma unroll
  for (int i = 0; i < 4; i++)
#pragma unroll
    for (int j = 0; j < 4; j++) acc[i][j] = f32x4{0.f, 0.f, 0.f, 0.f};
  const int wm = (wave >> 1) * 64, wn = (wave & 1) * 64;
  for (int kt = 0; kt < K; kt += 32){
    f32x4 a0a = *(const f32x4*)(Ag0 + kt), a0b = *(const f32x4*)(Ag0 + kt + 4);
    f32x4 a1a = *(const f32x4*)(Ag1 + kt), a1b = *(const f32x4*)(Ag1 + kt + 4);
    s16x8 bh0 = *(const s16x8*)(Bh0 + kt);
    s16x8 bh1 = *(const s16x8*)(Bh1 + kt);
    s16x8 bl0 = *(const s16x8*)(Bl0 + kt);
    s16x8 bl1 = *(const s16x8*)(Bl1 + kt);
    s16x8 h0, l0, h1, l1;
#pragma unroll
    for (int j = 0; j < 4; j++){
      u16 hh = f2b(a0a[j]); h0[j] = (short)hh; l0[j] = (short)f2b(a0a[j] - b2f(hh));
      hh = f2b(a0b[j]); h0[j+4] = (short)hh; l0[j+4] = (short)f2b(a0b[j] - b2f(hh));
      hh = f2b(a1a[j]); h1[j] = (short)hh; l1[j] = (short)f2b(a1a[j] - b2f(hh));
      hh = f2b(a1b[j]); h1[j+4] = (short)hh; l1[j+4] = (short)f2b(a1b[j] - b2f(hh));
    }
    __syncthreads();
    *(s16x8*)&Ah[r0 * 32 + seg] = h0;
    *(s16x8*)&Ah[(r0 + 64) * 32 + seg] = h1;
    *(s16x8*)&Al[r0 * 32 + seg] = l0;
    *(s16x8*)&Al[(r0 + 64) * 32 + seg] = l1;
    *(s16x8*)&Bh[r0 * 32 + seg] = bh0;
    *(s16x8*)&Bh[(r0 + 64) * 32 + seg] = bh1;
    *(s16x8*)&Bl[r0 * 32 + seg] = bl0;
    *(s16x8*)&Bl[(r0 + 64) * 32 + seg] = bl1;
    __syncthreads();
    s16x8 afh[4], afl[4], bfh[4], bfl[4];
#pragma unroll
    for (int i = 0; i < 4; i++){
      int ar = (wm + i * 16 + (l & 15)) * 32 + (l >> 4) * 8;
      int br = (wn + i * 16 + (l & 15)) * 32 + (l >> 4) * 8;
      afh[i] = *(const s16x8*)&Ah[ar];
      afl[i] = *(const s16x8*)&Al[ar];
      bfh[i] = *(const s16x8*)&Bh[br];
      bfl[i] = *(const s16x8*)&Bl[br];
    }
#pragma unroll
    for (int i = 0; i < 4; i++)
#pragma unroll
      for (int j = 0; j < 4; j++){
        acc[i][j] = __builtin_amdgcn_mfma_f32_16x16x32_bf16(afh[i], bfh[j], acc[i][j], 0, 0, 0);
        acc[i][j] = __builtin_amdgcn_mfma_f32_16x16x32_bf16(afh[i], bfl[j], acc[i][j], 0, 0, 0);
        acc[i][j] = __builtin_amdgcn_mfma_f32_16x16x32_bf16(afl[i], bfh[j], acc[i][j], 0, 0, 0);
      }
  }
#pragma unroll
  for (int i = 0; i < 4; i++)
#pragma unroll
    for (int r = 0; r < 4; r++){
      int row = m0 + wm + i * 16 + (l >> 4) * 4 + r;
#pragma unroll
      for (int j = 0; j < 4; j++){
        int col = n0 + wn + j * 16 + (l & 15);
        float v = acc[i][j][r];
        if (bias) v += bias[col];
        if (VTR){
          int bb = row >> 10, tq = row & 1023, hh = col >> 6, dd = col & 63;
          size_t vi = ((size_t)((bb << 4) + hh) * 64 + dd) * 1024 + tq;
          u16 hv = f2b(v);
          Ch[vi] = hv; Cl[vi] = f2b(v - b2f(hv));
        } else {
          size_t idx = (size_t)row * N + col;
          if (res) v += res[idx];
          if (Cf) Cf[idx] = v;
          if (Ch){ u16 hv = f2b(v); Ch[idx] = hv; Cl[idx] = f2b(v - b2f(hv)); }
        }
      }
    }
}

// ---------------- flash attention, split-precision, V^T from global ----------------
template<bool CAUSAL>
__global__ __launch_bounds__(512) void attn_sp_k(
    const u16* __restrict__ Qh, const u16* __restrict__ Ql,
    const u16* __restrict__ Kh, const u16* __restrict__ Kl,
    const u16* __restrict__ Vth, const u16* __restrict__ Vtl,
    const int* __restrict__ mask, float* __restrict__ O, int Tq, int Tk)
{
  __shared__ alignas(16) u16 Plh[8 * 512], Pll[8 * 512];
  const int tid = threadIdx.x, l = tid & 63, wave = tid >> 6;
  const int bh = blockIdx.y, b = bh >> 4, h = bh & 15;
  const int q0 = blockIdx.x * 128;
  const int qr = q0 + wave * 16 + (l & 15);
  s16x8 qah[2], qal[2];
#pragma unroll
  for (int kb = 0; kb < 2; kb++){
    size_t base = (size_t)(b * Tq + qr) * DM + h * 64 + kb * 32 + (l >> 4) * 8;
    qah[kb] = *(const s16x8*)(Qh + base);
    qal[kb] = *(const s16x8*)(Ql + base);
  }
  float mr[4], lr[4];
  f32x4 oacc[4];
#pragma unroll
  for (int r = 0; r < 4; r++){ mr[r] = -3e38f; lr[r] = 0.f; }
#pragma unroll
  for (int nb = 0; nb < 4; nb++) oacc[nb] = f32x4{0.f, 0.f, 0.f, 0.f};
  int wk = q0 + wave * 16 + 16;
  const int wklim = CAUSAL ? (wk < Tk ? wk : Tk) : Tk;
  const size_t vbase = (size_t)bh * 64 * 1024;
  for (int kt = 0; kt < wklim; kt += 32){
    s16x8 kfh[2][2], kfl[2][2];
#pragma unroll
    for (int n = 0; n < 2; n++)
#pragma unroll
      for (int kb = 0; kb < 2; kb++){
        size_t base = (size_t)(b * Tk + kt + n * 16 + (l & 15)) * DM + h * 64 + kb * 32 + (l >> 4) * 8;
        kfh[n][kb] = *(const s16x8*)(Kh + base);
        kfl[n][kb] = *(const s16x8*)(Kl + base);
      }
    f32x4 s0 = f32x4{0.f,0.f,0.f,0.f}, s1 = f32x4{0.f,0.f,0.f,0.f};
#pragma unroll
    for (int kb = 0; kb < 2; kb++){
      s0 = __builtin_amdgcn_mfma_f32_16x16x32_bf16(qah[kb], kfh[0][kb], s0, 0,0,0);
      s0 = __builtin_amdgcn_mfma_f32_16x16x32_bf16(qah[kb], kfl[0][kb], s0, 0,0,0);
      s0 = __builtin_amdgcn_mfma_f32_16x16x32_bf16(qal[kb], kfh[0][kb], s0, 0,0,0);
      s1 = __builtin_amdgcn_mfma_f32_16x16x32_bf16(qah[kb], kfh[1][kb], s1, 0,0,0);
      s1 = __builtin_amdgcn_mfma_f32_16x16x32_bf16(qah[kb], kfl[1][kb], s1, 0,0,0);
      s1 = __builtin_amdgcn_mfma_f32_16x16x32_bf16(qal[kb], kfh[1][kb], s1, 0,0,0);
    }
    int key0 = kt + (l & 15), key1 = key0 + 16;
    int mv0 = 1, mv1 = 1;
    if (!CAUSAL && mask){ mv0 = mask[b * Tk + key0]; mv1 = mask[b * Tk + key1]; }
#pragma unroll
    for (int r = 0; r < 4; r++){
      float a0 = s0[r] * 0.125f, a1 = s1[r] * 0.125f;
      if (CAUSAL){
        int qg = q0 + wave * 16 + (l >> 4) * 4 + r;
        if (key0 > qg) a0 = -1e30f;
        if (key1 > qg) a1 = -1e30f;
      } else {
        if (!mv0) a0 = -1e30f;
        if (!mv1) a1 = -1e30f;
      }
      float tm = fmaxf(a0, a1);
      tm = fmaxf(tm, __shfl_xor(tm, 1)); tm = fmaxf(tm, __shfl_xor(tm, 2));
      tm = fmaxf(tm, __shfl_xor(tm, 4)); tm = fmaxf(tm, __shfl_xor(tm, 8));
      float mn = fmaxf(mr[r], tm);
      float p0 = (a0 <= -1e29f) ? 0.f : exp2f((a0 - mn) * L2E);
      float p1 = (a1 <= -1e29f) ? 0.f : exp2f((a1 - mn) * L2E);
      float ts = p0 + p1;
      ts += __shfl_xor(ts, 1); ts += __shfl_xor(ts, 2);
      ts += __shfl_xor(ts, 4); ts += __shfl_xor(ts, 8);
      float corr = exp2f((mr[r] - mn) * L2E);
      lr[r] = lr[r] * corr + ts;
      mr[r] = mn;
#pragma unroll
      for (int nb = 0; nb < 4; nb++) oacc[nb][r] *= corr;
      int po = wave * 512 + ((l >> 4) * 4 + r) * 32 + (l & 15);
      u16 hh0 = f2b(p0), hh1 = f2b(p1);
      Plh[po] = hh0;      Pll[po] = f2b(p0 - b2f(hh0));
      Plh[po + 16] = hh1; Pll[po + 16] = f2b(p1 - b2f(hh1));
    }
    asm volatile("s_waitcnt lgkmcnt(0)" ::: "memory");
    __builtin_amdgcn_sched_barrier(0);
    s16x8 pah = *(const s16x8*)&Plh[wave * 512 + (l & 15) * 32 + (l >> 4) * 8];
    s16x8 pal = *(const s16x8*)&Pll[wave * 512 + (l & 15) * 32 + (l >> 4) * 8];
#pragma unroll
    for (int nb = 0; nb < 4; nb++){
      size_t vo = vbase + (size_t)(nb * 16 + (l & 15)) * 1024 + kt + (l >> 4) * 8;
      s16x8 vfh = *(const s16x8*)(Vth + vo);
      s16x8 vfl = *(const s16x8*)(Vtl + vo);
      oacc[nb] = __builtin_amdgcn_mfma_f32_16x16x32_bf16(pah, vfh, oacc[nb], 0, 0, 0);
      oacc[nb] = __builtin_amdgcn_mfma_f32_16x16x32_bf16(pah, vfl, oacc[nb], 0, 0, 0);
      oacc[nb] = __builtin_amdgcn_mfma_f32_16x16x32_bf16(pal, vfh, oacc[nb], 0, 0, 0);
    }
  }
#pragma unroll
  for (int r = 0; r < 4; r++){
    float inv = 1.0f / lr[r];
    int qg = q0 + wave * 16 + (l >> 4) * 4 + r;
#pragma unroll
    for (int nb = 0; nb < 4; nb++)
      O[(size_t)(b * Tq + qg) * DM + h * 64 + nb * 16 + (l & 15)] = oacc[nb][r] * inv;
  }
}

// ---------------- MoE gating: fp32, inline LN from H2 ----------------
__global__ __launch_bounds__(256) void moe_gate_k(const float* __restrict__ X,
    const float* __restrict__ g3, const float* __restrict__ b3,
    const float* __restrict__ wg, const float* __restrict__ bg,
    int* __restrict__ cnt, int* __restrict__ perm,
    int* __restrict__ toke, int* __restrict__ tokp, float* __restrict__ tokg)
{
  const int wave = threadIdx.x >> 6, l = threadIdx.x & 63;
  const int t = blockIdx.x * 4 + wave;
  float xv[16];
  float s = 0.f, sq = 0.f;
#pragma unroll
  for (int i = 0; i < 16; i++){
    xv[i] = X[(size_t)t * DM + l + i * 64];
    s += xv[i]; sq += xv[i] * xv[i];
  }
#pragma unroll
  for (int m = 1; m < 64; m <<= 1){ s += __shfl_xor(s, m); sq += __shfl_xor(sq, m); }
  float mean = s * (1.0f / DM);
  float var = sq * (1.0f / DM) - mean * mean;
  float rstd = rsqrtf(var + 1e-5f);
  float acc[8];
#pragma unroll
  for (int e = 0; e < 8; e++) acc[e] = 0.f;
#pragma unroll
  for (int i = 0; i < 16; i++){
    int k = l + i * 64;
    float xn = (xv[i] - mean) * rstd * g3[k] + b3[k];
    f32x4 wa = *(const f32x4*)&wg[k * 8];
    f32x4 wb = *(const f32x4*)&wg[k * 8 + 4];
#pragma unroll
    for (int j = 0; j < 4; j++){ acc[j] += xn * wa[j]; acc[4 + j] += xn * wb[j]; }
  }
#pragma unroll
  for (int e = 0; e < 8; e++)
#pragma unroll
    for (int m = 1; m < 64; m <<= 1) acc[e] += __shfl_xor(acc[e], m);
  if (l == 0){
    float lg[8];
#pragma unroll
    for (int e = 0; e < 8; e++) lg[e] = acc[e] + bg[e];
    float mx = lg[0];
#pragma unroll
    for (int e = 1; e < 8; e++) mx = fmaxf(mx, lg[e]);
    float ex[8]; float sum = 0.f;
#pragma unroll
    for (int e = 0; e < 8; e++){ ex[e] = expf(lg[e] - mx); sum += ex[e]; }
    int i0 = 0;
    for (int e = 1; e < 8; e++) if (ex[e] > ex[i0]) i0 = e;
    int i1 = (i0 == 0) ? 1 : 0;
    for (int e = 0; e < 8; e++) if (e != i0 && ex[e] > ex[i1]) i1 = e;
    float p0 = ex[i0] / sum, p1 = ex[i1] / sum;
    float gs = p0 + p1;
    int pos0 = atomicAdd(&cnt[i0], 1);
    int pos1 = atomicAdd(&cnt[i1], 1);
    perm[i0 * 4096 + pos0] = t;
    perm[i1 * 4096 + pos1] = t;
    toke[2 * t] = i0; toke[2 * t + 1] = i1;
    tokp[2 * t] = pos0; tokp[2 * t + 1] = pos1;
    tokg[2 * t] = p0 / gs; tokg[2 * t + 1] = p1 / gs;
  }
}

__global__ void offsets_k(const int* __restrict__ cnt, int* __restrict__ off){
  if (threadIdx.x == 0){
    int a = 0;
    for (int e = 0; e < 8; e++){ off[e] = a; a += cnt[e]; }
  }
}

// ---------------- MoE grouped GEMMs (plain bf16) ----------------
__global__ __launch_bounds__(256) void gemm_moe1_k(
    const u16* __restrict__ X, const u16* __restrict__ W1t, const float* __restrict__ b1,
    const int* __restrict__ perm, const int* __restrict__ cnt, const int* __restrict__ off,
    u16* __restrict__ Hb)
{
  const int e = blockIdx.z;
  const int Ce = cnt[e];
  const int mt = blockIdx.y;
  if (mt * 128 >= Ce) return;
  __shared__ alignas(16) u16 Asl[128 * 32];
  __shared__ alignas(16) u16 Bsl[128 * 32];
  const int tid = threadIdx.x, l = tid & 63, wave = tid >> 6;
  const int n0 = blockIdx.x * 128;
  const int r0 = tid >> 2, seg = (tid & 3) * 8;
  const int rl0 = mt * 128 + r0, rl1 = rl0 + 64;
  const int g0 = perm[e * 4096 + (rl0 < Ce ? rl0 : Ce - 1)];
  const int g1 = perm[e * 4096 + (rl1 < Ce ? rl1 : Ce - 1)];
  const u16* Ag0 = X + (size_t)g0 * DM + seg;
  const u16* Ag1 = X + (size_t)g1 * DM + seg;
  const u16* Bg0 = W1t + (size_t)e * FFD * DM + (size_t)(n0 + r0) * DM + seg;
  const u16* Bg1 = Bg0 + (size_t)64 * DM;
  f32x4 acc[4][4];
#pragma unroll
  for (int i = 0; i < 4; i++)
#pragma unroll
    for (int j = 0; j < 4; j++) acc[i][j] = f32x4{0.f,0.f,0.f,0.f};
  const int wm = (wave >> 1) * 64, wn = (wave & 1) * 64;
  for (int kt = 0; kt < DM; kt += 32){
    s16x8 a0 = *(const s16x8*)(Ag0 + kt);
    s16x8 a1 = *(const s16x8*)(Ag1 + kt);
    s16x8 b0 = *(const s16x8*)(Bg0 + kt);
    s16x8 b1v = *(const s16x8*)(Bg1 + kt);
    __syncthreads();
    *(s16x8*)&Asl[r0 * 32 + seg] = a0;
    *(s16x8*)&Asl[(r0 + 64) * 32 + seg] = a1;
    *(s16x8*)&Bsl[r0 * 32 + seg] = b0;
    *(s16x8*)&Bsl[(r0 + 64) * 32 + seg] = b1v;
    __syncthreads();
    s16x8 af[4], bfr[4];
#pragma unroll
    for (int i = 0; i < 4; i++){
      af[i]  = *(const s16x8*)&Asl[(wm + i * 16 + (l & 15)) * 32 + (l >> 4) * 8];
      bfr[i] = *(const s16x8*)&Bsl[(wn + i * 16 + (l & 15)) * 32 + (l >> 4) * 8];
    }
#pragma unroll
    for (int i = 0; i < 4; i++)
#pragma unroll
      for (int j = 0; j < 4; j++)
        acc[i][j] = __builtin_amdgcn_mfma_f32_16x16x32_bf16(af[i], bfr[j], acc[i][j], 0, 0, 0);
  }
  const int base = off[e];
#pragma unroll
  for (int i = 0; i < 4; i++)
#pragma unroll
    for (int r = 0; r < 4; r++){
      int rloc = mt * 128 + wm + i * 16 + (l >> 4) * 4 + r;
      if (rloc < Ce){
#pragma unroll
        for (int j = 0; j < 4; j++){
          int col = n0 + wn + j * 16 + (l & 15);
          float v = acc[i][j][r] + b1[e * FFD + col];
          v = fmaxf(v, 0.f);
          Hb[(size_t)(base + rloc) * FFD + col] = f2b(v);
        }
      }
    }
}

__global__ __launch_bounds__(256) void gemm_moe2_k(
    const u16* __restrict__ Hb, const u16* __restrict__ W2t,
    const int* __restrict__ cnt, const int* __restrict__ off, float* __restrict__ Y)
{
  const int e = blockIdx.z;
  const int Ce = cnt[e];
  const int mt = blockIdx.y;
  if (mt * 128 >= Ce) return;
  __shared__ alignas(16) u16 Asl[128 * 32];
  __shared__ alignas(16) u16 Bsl[128 * 32];
  const int tid = threadIdx.x, l = tid & 63, wave = tid >> 6;
  const int n0 = blockIdx.x * 128;
  const int r0 = tid >> 2, seg = (tid & 3) * 8;
  const int base = off[e];
  const int rl0 = mt * 128 + r0, rl1 = rl0 + 64;
  const int a0r = base + (rl0 < Ce ? rl0 : Ce - 1);
  const int a1r = base + (rl1 < Ce ? rl1 : Ce - 1);
  const u16* Ag0 = Hb + (size_t)a0r * FFD + seg;
  const u16* Ag1 = Hb + (size_t)a1r * FFD + seg;
  const u16* Bg0 = W2t + (size_t)e * DM * FFD + (size_t)(n0 + r0) * FFD + seg;
  const u16* Bg1 = Bg0 + (size_t)64 * FFD;
  f32x4 acc[4][4];
#pragma unroll
  for (int i = 0; i < 4; i++)
#pragma unroll
    for (int j = 0; j < 4; j++) acc[i][j] = f32x4{0.f,0.f,0.f,0.f};
  const int wm = (wave >> 1) * 64, wn = (wave & 1) * 64;
  for (int kt = 0; kt < FFD; kt += 32){
    s16x8 a0 = *(const s16x8*)(Ag0 + kt);
    s16x8 a1 = *(const s16x8*)(Ag1 + kt);
    s16x8 b0 = *(const s16x8*)(Bg0 + kt);
    s16x8 b1v = *(const s16x8*)(Bg1 + kt);
    __syncthreads();
    *(s16x8*)&Asl[r0 * 32 + seg] = a0;
    *(s16x8*)&Asl[(r0 + 64) * 32 + seg] = a1;
    *(s16x8*)&Bsl[r0 * 32 + seg] = b0;
    *(s16x8*)&Bsl[(r0 + 64) * 32 + seg] = b1v;
    __syncthreads();
    s16x8 af[4], bfr[4];
#pragma unroll
    for (int i = 0; i < 4; i++){
      af[i]  = *(const s16x8*)&Asl[(wm + i * 16 + (l & 15)) * 32 + (l >> 4) * 8];
      bfr[i] = *(const s16x8*)&Bsl[(wn + i * 16 + (l & 15)) * 32 + (l >> 4) * 8];
    }
#pragma unroll
    for (int i = 0; i < 4; i++)
#pragma unroll
      for (int j = 0; j < 4; j++)
        acc[i][j] = __builtin_amdgcn_mfma_f32_16x16x32_bf16(af[i], bfr[j], acc[i][j], 0, 0, 0);
  }
#pragma unroll
  for (int i = 0; i < 4; i++)
#pragma unroll
    for (int r = 0; r < 4; r++){
      int rloc = mt * 128 + wm + i * 16 + (l >> 4) * 4 + r;
      if (rloc < Ce){
#pragma unroll
        for (int j = 0; j < 4; j++){
          int col = n0 + wn + j * 16 + (l & 15);
          Y[(size_t)(base + rloc) * DM + col] = acc[i][j][r];
        }
      }
    }
}

__global__ __launch_bounds__(256) void combine_k(const float* __restrict__ h2, const float* __restrict__ Y,
    const int* __restrict__ toke, const int* __restrict__ tokp, const float* __restrict__ tokg,
    const int* __restrict__ off, const float* __restrict__ b2, float* __restrict__ out)
{
  const int t = blockIdx.x;
  const int c = threadIdx.x * 4;
  int e0 = toke[2 * t], e1 = toke[2 * t + 1];
  size_t r0 = (size_t)off[e0] + tokp[2 * t];
  size_t r1 = (size_t)off[e1] + tokp[2 * t + 1];
  float g0 = tokg[2 * t], g1 = tokg[2 * t + 1];
  f32x4 a  = *(const f32x4*)&h2[(size_t)t * DM + c];
  f32x4 y0 = *(const f32x4*)&Y[r0 * DM + c];
  f32x4 y1 = *(const f32x4*)&Y[r1 * DM + c];
  f32x4 v0 = *(const f32x4*)&b2[(size_t)e0 * DM + c];
  f32x4 v1 = *(const f32x4*)&b2[(size_t)e1 * DM + c];
  f32x4 o = a + (y0 + v0) * g0 + (y1 + v1) * g1;
  *(f32x4*)&out[(size_t)t * DM + c] = o;
}

// ---------------- host ----------------
extern "C" void kernel_launch(void* const* d_in, const int* in_sizes, int n_in,
                              void* d_out, int out_size, void* d_ws, size_t ws_size,
                              hipStream_t stream) {
  const float* x    = (const float*)d_in[0];
  const float* enc  = (const float*)d_in[1];
  const int* smask  = (const int*)d_in[2];
  const float* ln1g = (const float*)d_in[4]; const float* ln1b = (const float*)d_in[5];
  const float* ln2g = (const float*)d_in[6]; const float* ln2b = (const float*)d_in[7];
  const float* ln3g = (const float*)d_in[8]; const float* ln3b = (const float*)d_in[9];
  const float* wq1 = (const float*)d_in[10]; const float* bq1 = (const float*)d_in[11];
  const float* wk1 = (const float*)d_in[12]; const float* bk1 = (const float*)d_in[13];
  const float* wv1 = (const float*)d_in[14]; const float* bv1 = (const float*)d_in[15];
  const float* wo1 = (const float*)d_in[16]; const float* bo1 = (const float*)d_in[17];
  const float* wq2 = (const float*)d_in[18]; const float* bq2 = (const float*)d_in[19];
  const float* wk2 = (const float*)d_in[20]; const float* bk2 = (const float*)d_in[21];
  const float* wv2 = (const float*)d_in[22]; const float* bv2 = (const float*)d_in[23];
  const float* wo2 = (const float*)d_in[24]; const float* bo2 = (const float*)d_in[25];
  const float* wg  = (const float*)d_in[26]; const float* bg  = (const float*)d_in[27];
  const float* w1  = (const float*)d_in[28]; const float* b1  = (const float*)d_in[29];
  const float* w2  = (const float*)d_in[30]; const float* b2  = (const float*)d_in[31];

  const size_t MB = 1024ull * 1024ull;
  char* ws = (char*)d_ws;
  size_t o = 0;
  auto alloc = [&](size_t bytes) -> void* {
    void* p = ws + o;
    o += (bytes + 255) & ~(size_t)255;
    return p;
  };
  // persistent
  float* H1  = (float*)alloc(16 * MB);
  float* H2  = (float*)alloc(16 * MB);
  u16*  NBF  = (u16*) alloc(8 * MB);
  float* NF32= (float*)alloc(16 * MB);
  int* CNT  = (int*)alloc(256);
  int* OFF  = (int*)alloc(256);
  int* PERM = (int*)alloc((size_t)8 * 4096 * 4);
  int* TOKE = (int*)alloc((size_t)NTOK * 2 * 4);
  int* TOKP = (int*)alloc((size_t)NTOK * 2 * 4);
  float* TOKG = (float*)alloc((size_t)NTOK * 2 * 4);
  // phase-overlapped region (224 MiB): phase1 = attention, phase2 = MoE
  char* R = (char*)alloc(224 * MB);
  u16* WTH = (u16*)(R);              // 16 MB  (8 attn weights, hi)
  u16* WTL = (u16*)(R + 16 * MB);    // 16 MB  (lo)
  u16* QH  = (u16*)(R + 32 * MB);    // 8 MB
  u16* QL  = (u16*)(R + 40 * MB);
  u16* KH  = (u16*)(R + 48 * MB);
  u16* KL  = (u16*)(R + 56 * MB);
  u16* VTH = (u16*)(R + 64 * MB);    // V^T [B*H][64][1024] hi
  u16* VTL = (u16*)(R + 72 * MB);
  float* OF32 = (float*)(R + 80 * MB); // 16 MB, ends at 96 MB
  u16* W1T = (u16*)(R);              // 64 MB [E][FF][D]   (phase 2 overlays phase 1)
  u16* W2T = (u16*)(R + 64 * MB);    // 64 MB [E][D][FF]
  u16* HB  = (u16*)(R + 128 * MB);   // 64 MB
  float* YB = (float*)(R + 192 * MB);// 32 MB, ends at 224 MB

  // attn weights -> bf16 hi/lo transposed
  Ptr8 p8; p8.p[0]=wq1; p8.p[1]=wk1; p8.p[2]=wv1; p8.p[3]=wo1;
           p8.p[4]=wq2; p8.p[5]=wk2; p8.p[6]=wv2; p8.p[7]=wo2;
  trans8_k<<<dim3(16,16,8), 256, 0, stream>>>(p8, WTH, WTL);

  // ---- self-attention ----
  ln_k<<<dim3(NTOK), 256, 0, stream>>>(x, ln1g, ln1b, NF32, nullptr);
  gemm_sp_k<0><<<dim3(8,32), 256, 0, stream>>>(NF32, WTH + (size_t)0*1024*1024, WTL + (size_t)0*1024*1024, bq1, nullptr, nullptr, QH, QL, NTOK, DM, DM);
  gemm_sp_k<0><<<dim3(8,32), 256, 0, stream>>>(NF32, WTH + (size_t)1*1024*1024, WTL + (size_t)1*1024*1024, bk1, nullptr, nullptr, KH, KL, NTOK, DM, DM);
  gemm_sp_k<1><<<dim3(8,32), 256, 0, stream>>>(NF32, WTH + (size_t)2*1024*1024, WTL + (size_t)2*1024*1024, bv1, nullptr, nullptr, VTH, VTL, NTOK, DM, DM);
  attn_sp_k<true><<<dim3(8,64), 512, 0, stream>>>(QH, QL, KH, KL, VTH, VTL, nullptr, OF32, TT, TT);
  gemm_sp_k<0><<<dim3(8,32), 256, 0, stream>>>(OF32, WTH + (size_t)3*1024*1024, WTL + (size_t)3*1024*1024, bo1, x, H1, nullptr, nullptr, NTOK, DM, DM);

  // ---- cross-attention ----
  ln_k<<<dim3(NTOK), 256, 0, stream>>>(H1, ln2g, ln2b, NF32, nullptr);
  gemm_sp_k<0><<<dim3(8,32), 256, 0, stream>>>(NF32, WTH + (size_t)4*1024*1024, WTL + (size_t)4*1024*1024, bq2, nullptr, nullptr, QH, QL, NTOK, DM, DM);
  gemm_sp_k<0><<<dim3(8,32), 256, 0, stream>>>(enc,  WTH + (size_t)5*1024*1024, WTL + (size_t)5*1024*1024, bk2, nullptr, nullptr, KH, KL, NTOK, DM, DM);
  gemm_sp_k<1><<<dim3(8,32), 256, 0, stream>>>(enc,  WTH + (size_t)6*1024*1024, WTL + (size_t)6*1024*1024, bv2, nullptr, nullptr, VTH, VTL, NTOK, DM, DM);
  attn_sp_k<false><<<dim3(8,64), 512, 0, stream>>>(QH, QL, KH, KL, VTH, VTL, smask, OF32, TT, TT);
  gemm_sp_k<0><<<dim3(8,32), 256, 0, stream>>>(OF32, WTH + (size_t)7*1024*1024, WTL + (size_t)7*1024*1024, bo2, H1, H2, nullptr, nullptr, NTOK, DM, DM);

  // ---- MoE (phase 2 overlays phase-1 buffers; launched after last phase-1 reader) ----
  transb_k<<<dim3(64,16,8), 256, 0, stream>>>(w1, W1T, 1024, 4096);
  transb_k<<<dim3(16,64,8), 256, 0, stream>>>(w2, W2T, 4096, 1024);
  ln_k<<<dim3(NTOK), 256, 0, stream>>>(H2, ln3g, ln3b, nullptr, NBF);
  hipMemsetAsync(CNT, 0, 8 * sizeof(int), stream);
  moe_gate_k<<<dim3(1024), 256, 0, stream>>>(H2, ln3g, ln3b, wg, bg, CNT, PERM, TOKE, TOKP, TOKG);
  offsets_k<<<dim3(1), 64, 0, stream>>>(CNT, OFF);
  gemm_moe1_k<<<dim3(32,32,8), 256, 0, stream>>>(NBF, W1T, b1, PERM, CNT, OFF, HB);
  gemm_moe2_k<<<dim3(8,32,8), 256, 0, stream>>>(HB, W2T, CNT, OFF, YB);
  combine_k<<<dim3(NTOK), 256, 0, stream>>>(H2, YB, TOKE, TOKP, TOKG, OFF, b2, (float*)d_out);
}